// Round 4
// baseline (6524.127 us; speedup 1.0000x reference)
//
#include <hip/hip_runtime.h>
#include <math.h>

// DEC_LO exactly as in the reference; DEC_HI[k] = (-1)^(k+1) * DEC_LO[11-k]
__constant__ float F_LO[12] = {
    -0.00107730108499558f,  0.004777257511010651f, 0.0005538422009938016f,
    -0.031582039318031156f, 0.02752286553001629f,  0.09750160558707936f,
    -0.12976686756709563f,  -0.22626469396516913f, 0.3152503517092432f,
    0.7511339080215775f,    0.4946238903983854f,   0.11154074335008017f };
__constant__ float F_HI[12] = {
    -0.11154074335008017f,  0.4946238903983854f,   -0.7511339080215775f,
    0.3152503517092432f,    0.22626469396516913f,  -0.12976686756709563f,
    -0.09750160558707936f,  0.02752286553001629f,  0.031582039318031156f,
    0.0005538422009938016f, -0.004777257511010651f, -0.00107730108499558f };

__device__ __forceinline__ int reflect_idx(int i, int N) {
    while (i < 0 || i >= N) {
        if (i < 0) i = -1 - i;
        else       i = 2 * N - 1 - i;
    }
    return i;
}

__device__ __forceinline__ float gelu_f(float x) {
    return 0.5f * x * (1.0f + erff(x * 0.7071067811865475f));
}

#define GSL(total) for (long idx = (long)blockIdx.x * blockDim.x + threadIdx.x; \
                        idx < (total); idx += (long)gridDim.x * blockDim.x)

// ---------------- diagnostic fill (guard path) ------------------------------------
__global__ void fill_kernel(float* __restrict__ out, long n, float v)
{
    GSL(n) out[idx] = v;
}

// ---------------- fc0: x(8,255,255,4)@(4,48)+b -> A(8,48,256,256), zero pad to 256 --
__global__ void fc0_kernel(const float* __restrict__ x, const float* __restrict__ w,
                           const float* __restrict__ b, float* __restrict__ out)
{
    GSL(8L * 48 * 65536) {
        int xx = idx & 255;
        int y  = ((int)(idx >> 8)) & 255;
        int bc = (int)(idx >> 16);          // b*48 + c
        int c  = bc % 48;
        float v = 0.f;
        if (y < 255 && xx < 255) {
            int bb = bc / 48;
            const float* xp = x + (((size_t)(bb * 255 + y) * 255 + xx) << 2);
            v = b[c] + xp[0] * w[c] + xp[1] * w[48 + c] + xp[2] * w[96 + c] + xp[3] * w[144 + c];
        }
        out[idx] = v;
    }
}

// ---------------- fused separable 2D analysis: in (R,N,N) -> 4 subbands (R,O,O) ----
// O = (N+11)/2. Block = one 32x32 output tile of one sheet.
// Phase 1: stage a 75x75 input tile (symmetric reflection) into LDS, PARITY-SPLIT
//   per row: even cols at [m*80 + 0..37], odd cols at [m*80 + 40 + 0..36]. The
//   x-pass then reads stride-1 (conflict-free) instead of stride-2 (4-way).
// Phase 2: x-pass into REGISTERS (10 items/thread, unrolled -> no scratch).
// Phase 3: write lo/hi back into the SAME LDS buffer (75x64 <= 75x80), y-pass.
// LDS = 24000 B (was 41984) -> 6 blocks/CU instead of 3.
__global__ __launch_bounds__(256) void dwt2_kernel(
        const float* __restrict__ in, float* __restrict__ ll,
        float* __restrict__ d0, float* __restrict__ d1, float* __restrict__ d2,
        int R, int N, int O, int T)
{
    __shared__ float s_a[75 * 80];
    int tid = threadIdx.x;
    int bid = blockIdx.x;
    int tiles = T * T;
    int r = bid / tiles;
    int trem = bid % tiles;
    int V0 = (trem / T) * 32;
    int U0 = (trem % T) * 32;
    const float* sheet = in + (size_t)r * N * N;
    int gr0 = 2 * V0 - 10, gc0 = 2 * U0 - 10;
    for (int lin = tid; lin < 75 * 75; lin += 256) {
        int i = lin / 75, j = lin % 75;
        int gi = reflect_idx(gr0 + i, N);
        int gj = reflect_idx(gc0 + j, N);
        s_a[i * 80 + ((j & 1) ? 40 : 0) + (j >> 1)] = sheet[(size_t)gi * N + gj];
    }
    __syncthreads();
    // x-pass: 75 rows x 32 u = 2400 items into registers
    float rl[10], rh[10];
    #pragma unroll
    for (int it = 0; it < 10; ++it) {
        int lin = it * 256 + tid;
        if (lin < 2400) {
            int m = lin >> 5, u = lin & 31;
            const float* pe = s_a + m * 80 + u;        // even-col taps e[u..u+5]
            const float* po = pe + 40;                 // odd-col taps  o[u..u+5]
            float la = 0.f, ha = 0.f;
            #pragma unroll
            for (int t = 0; t < 6; ++t) {
                float ve = pe[t], vo = po[t];
                la += ve * F_LO[11 - 2 * t] + vo * F_LO[10 - 2 * t];
                ha += ve * F_HI[11 - 2 * t] + vo * F_HI[10 - 2 * t];
            }
            rl[it] = la; rh[it] = ha;
        }
    }
    __syncthreads();
    #pragma unroll
    for (int it = 0; it < 10; ++it) {
        int lin = it * 256 + tid;
        if (lin < 2400) {
            int m = lin >> 5, u = lin & 31;
            s_a[m * 64 + u]      = rl[it];
            s_a[m * 64 + 32 + u] = rh[it];
        }
    }
    __syncthreads();
    // y-pass: 32x32 outputs x 4 subbands
    int u = tid & 31;
    #pragma unroll
    for (int it = 0; it < 4; ++it) {
        int v = it * 8 + (tid >> 5);
        int ov = V0 + v, ou = U0 + u;
        if (ov < O && ou < O) {
            const float* pl = s_a + (2 * v) * 64 + u;
            const float* ph = pl + 32;
            float a_ll = 0.f, a_lh = 0.f, a_hl = 0.f, a_hh = 0.f;
            #pragma unroll
            for (int k = 0; k < 12; ++k) {
                float cl = F_LO[11 - k], cf = F_HI[11 - k];
                float vl = pl[k * 64], vh = ph[k * 64];
                a_ll += vl * cl;  a_lh += vl * cf;
                a_hl += vh * cl;  a_hh += vh * cf;
            }
            size_t o = ((size_t)r * O + ov) * O + ou;
            ll[o] = a_ll; d0[o] = a_lh; d1[o] = a_hl; d2[o] = a_hh;
        }
    }
}

// ---------------- fused separable 2D synthesis (interior-only levels) --------------
// ll,d0,d1,d2: (R,n,n) tight. out: (R,OD,OD), OD = 2n-10. TO = tile dim (even, <=36).
__global__ __launch_bounds__(256) void idwt2_kernel(
        const float* __restrict__ ll, const float* __restrict__ d0,
        const float* __restrict__ d1, const float* __restrict__ d2,
        float* __restrict__ out, int R, int n, int OD, int TO, int T)
{
    __shared__ float s_sub[4][24 * 24];
    __shared__ float s_wl[36 * 24];
    __shared__ float s_wh[36 * 24];
    int tid = threadIdx.x;
    int bid = blockIdx.x;
    int tiles = T * T;
    int r = bid / tiles;
    int trem = bid % tiles;
    int Y0t = (trem / T) * TO;
    int X0t = (trem % T) * TO;
    int ir0 = Y0t >> 1, ic0 = X0t >> 1;
    size_t sho = (size_t)r * n * n;
    const float* subs0 = ll + sho;
    const float* subs1 = d0 + sho;
    const float* subs2 = d1 + sho;
    const float* subs3 = d2 + sho;
    for (int lin = tid; lin < 4 * 576; lin += 256) {
        int q = lin / 576;
        int rem = lin % 576;
        int i = rem / 24, j = rem % 24;
        int gi = ir0 + i; if (gi > n - 1) gi = n - 1;   // clamped loads are unused
        int gj = ic0 + j; if (gj > n - 1) gj = n - 1;
        const float* s = (q == 0) ? subs0 : (q == 1) ? subs1 : (q == 2) ? subs2 : subs3;
        s_sub[q][rem] = s[(size_t)gi * n + gj];
    }
    __syncthreads();
    int NW = (TO >> 1) + 6;
    for (int lin = tid; lin < TO * NW; lin += 256) {
        int i = lin % NW, y = lin / NW;
        int par = y & 1;
        int roff = (y >> 1) * 24 + i;
        const float* pll = s_sub[0] + roff;
        const float* pd0 = s_sub[1] + roff;
        const float* pd1 = s_sub[2] + roff;
        const float* pd2 = s_sub[3] + roff;
        float wl = 0.f, wh = 0.f;
        #pragma unroll
        for (int t = 0; t < 6; ++t) {
            float cl = F_LO[2 * t + 1 - par], chf = F_HI[2 * t + 1 - par];
            wl += pll[t * 24] * cl + pd0[t * 24] * chf;
            wh += pd1[t * 24] * cl + pd2[t * 24] * chf;
        }
        s_wl[y * 24 + i] = wl;
        s_wh[y * 24 + i] = wh;
    }
    __syncthreads();
    for (int lin = tid; lin < TO * TO; lin += 256) {
        int tx = lin % TO, ty = lin / TO;
        int oy = Y0t + ty, ox = X0t + tx;
        if (oy >= OD || ox >= OD) continue;
        int par = tx & 1;
        const float* pl = s_wl + ty * 24 + (tx >> 1);
        const float* ph = s_wh + ty * 24 + (tx >> 1);
        float acc = 0.f;
        #pragma unroll
        for (int s = 0; s < 6; ++s)
            acc += pl[s] * F_LO[2 * s + 1 - par] + ph[s] * F_HI[2 * s + 1 - par];
        out[((size_t)r * OD + oy) * OD + ox] = acc;
    }
}

// ---------------- synthesis along y, TWO independent problems in one launch --------
__global__ void idwt_y_pair_kernel(
        const float* __restrict__ loA, const float* __restrict__ hiA, float* __restrict__ outA,
        int rslA, int sslA, int rshA, int sshA,
        const float* __restrict__ loB, const float* __restrict__ hiB, float* __restrict__ outB,
        int rslB, int sslB, int rshB, int sshB,
        int R, int n, int NX)
{
    int OY = 2 * n - 10;
    long base = (long)R * OY * NX;
    GSL(2 * base) {
        const float *lo, *hi; float* out; int rsl, ssl, rsh, ssh; long id2;
        if (idx < base) { lo=loA; hi=hiA; out=outA; rsl=rslA; ssl=sslA; rsh=rshA; ssh=sshA; id2=idx; }
        else            { lo=loB; hi=hiB; out=outB; rsl=rslB; ssl=sslB; rsh=rshB; ssh=sshB; id2=idx-base; }
        int x = (int)(id2 % NX);
        long t = id2 / NX;
        int u = (int)(t % OY);
        int r = (int)(t / OY);
        int par = u & 1;
        int i0  = u >> 1;
        float cl[6], ch[6];
        #pragma unroll
        for (int tt = 0; tt < 6; ++tt) {
            cl[tt] = F_LO[2 * tt + 1 - par];
            ch[tt] = F_HI[2 * tt + 1 - par];
        }
        const float* lop = lo + (size_t)r * ssl + (size_t)i0 * rsl + x;
        const float* hp  = hi + (size_t)r * ssh + (size_t)i0 * rsh + x;
        float acc = 0.f;
        #pragma unroll
        for (int tt = 0; tt < 6; ++tt)
            acc += lop[(size_t)tt * rsl] * cl[tt] + hp[(size_t)tt * rsh] * ch[tt];
        out[((size_t)r * OY + u) * NX + x] = acc;
    }
}

// ---------------- all four coarsest mixes in ONE launch ----------------------------
__global__ void mix4_kernel(const float* __restrict__ L3, const float* __restrict__ Y2,
                            const float* __restrict__ wc_l, float* __restrict__ L3m,
                            float* __restrict__ Y2m, long D3, int NB)
{
    const long PER = 48L * 1681;
    const size_t WKS = 48 * 48 * (size_t)1681;
    GSL(4 * PER) {
        int q = (int)(idx / PER);
        long r = idx % PER;
        const float* in = (q == 0) ? L3 : Y2 + (size_t)(q - 1) * D3;
        const float* wk = wc_l + (size_t)q * WKS;
        float* out      = (q == 0) ? L3m : Y2m + (size_t)(q - 1) * D3;
        int p = (int)(r % 1681);
        int o = (int)(r / 1681);
        float acc[8] = {0.f,0.f,0.f,0.f,0.f,0.f,0.f,0.f};
        for (int i = 0; i < 48; ++i) {
            float w = wk[(size_t)(i * 48 + o) * 1681 + p];
            for (int b = 0; b < NB; ++b)
                acc[b] += in[(size_t)(b * 48 + i) * 1681 + p] * w;
        }
        for (int b = 0; b < NB; ++b)
            out[(size_t)(b * 48 + o) * 1681 + p] = acc[b];
    }
}

// ---------------- fused: IDWT-L1 row synthesis + h = act(h1 + cw@h + cb), in place -
// Block = (local batch b, row y, x-tile of 64 px). Thread owns ONE pixel xx and
// TWELVE output channels (cg..cg+11): the s_h[i][xx] read is shared across all 12
// channels (48 LDS reads/thread instead of 576), and weights are wave-uniform
// float4 broadcasts from a transposed stride-52 (conflict-free, 16B-aligned) s_wt.
__global__ __launch_bounds__(256) void idwt_x_combine_kernel(
        const float* __restrict__ w1a, const float* __restrict__ w1b,
        float* __restrict__ h, const float* __restrict__ cw,
        const float* __restrict__ cb, int do_gelu)
{
    __shared__ float s_h[48 * 64];      // [i][xx]
    __shared__ float s_wt[48 * 52];     // transposed: [i][o], stride 52
    __shared__ float s_b[48];
    int tid = threadIdx.x;
    int bi = blockIdx.x;
    int xt = bi & 3;
    int y  = (bi >> 2) & 255;
    int b  = bi >> 10;
    int x0 = xt << 6;
    // s_wt[i*52+o] = cw[o*48+i]; destination-major loop -> conflict-free LDS writes
    for (int d = tid; d < 48 * 52; d += 256) {
        int i = d / 52, o = d - i * 52;
        if (o < 48) s_wt[d] = cw[o * 48 + i];
    }
    if (tid < 48) s_b[tid] = cb[tid];
    for (int j = tid; j < 48 * 64; j += 256) {
        int i = j >> 6, xx = j & 63;
        s_h[j] = h[((size_t)(b * 48 + i) * 256 + y) * 256 + x0 + xx];
    }
    __syncthreads();
    int xx = tid & 63;
    int cg = (tid >> 6) * 12;           // wave-uniform channel group
    int x  = x0 + xx;
    int par = x & 1;
    int i0  = x >> 1;                   // i0+5 <= 132 < 133, no bounds check needed
    float cl[6], chv[6];
    #pragma unroll
    for (int tt = 0; tt < 6; ++tt) {
        cl[tt]  = F_LO[2 * tt + 1 - par];
        chv[tt] = F_HI[2 * tt + 1 - par];
    }
    float acc[12];
    #pragma unroll
    for (int cc = 0; cc < 12; ++cc) acc[cc] = s_b[cg + cc];
    // channel mix: acc[cc] += sum_i h_old[i][xx] * w[cg+cc][i]
    for (int i = 0; i < 48; ++i) {
        float vi = s_h[i * 64 + xx];
        const float4* w4 = (const float4*)(s_wt + i * 52 + cg);  // 16B aligned
        float4 a = w4[0], b4 = w4[1], c4 = w4[2];
        acc[0] += vi * a.x;  acc[1] += vi * a.y;  acc[2]  += vi * a.z;  acc[3]  += vi * a.w;
        acc[4] += vi * b4.x; acc[5] += vi * b4.y; acc[6]  += vi * b4.z; acc[7]  += vi * b4.w;
        acc[8] += vi * c4.x; acc[9] += vi * c4.y; acc[10] += vi * c4.z; acc[11] += vi * c4.w;
    }
    // per-channel IDWT-L1 row synthesis taps + store
    #pragma unroll
    for (int cc = 0; cc < 12; ++cc) {
        int c = cg + cc;
        const float* lop = w1a + ((size_t)(b * 48 + c) * 256 + y) * 133 + i0;
        const float* hp  = w1b + ((size_t)(b * 48 + c) * 256 + y) * 133 + i0;
        float h1 = 0.f;
        #pragma unroll
        for (int tt = 0; tt < 6; ++tt)
            h1 += lop[tt] * cl[tt] + hp[tt] * chv[tt];
        float r = h1 + acc[cc];
        h[((size_t)(b * 48 + c) * 256 + y) * 256 + x] = do_gelu ? gelu_f(r) : r;
    }
}

// ---------------- head: crop 255x255, gelu(h@fc1+b1)@fc2+b2 ------------------------
__global__ __launch_bounds__(256) void head_kernel(const float* __restrict__ h,
        const float* __restrict__ w1, const float* __restrict__ b1,
        const float* __restrict__ w2, const float* __restrict__ b2,
        float* __restrict__ out)
{
    __shared__ float4 s_w1[768];      // [i][hh/4]
    __shared__ float s_b1[64];
    __shared__ float s_w2[64];
    int tid = threadIdx.x;
    for (int j = tid; j < 768; j += 256) s_w1[j] = ((const float4*)w1)[j];
    if (tid < 64) { s_b1[tid] = b1[tid]; s_w2[tid] = w2[tid]; }
    __syncthreads();
    int b = blockIdx.x / 255;
    int y = blockIdx.x % 255;
    if (tid >= 255) return;
    float v[48];
    #pragma unroll
    for (int c = 0; c < 48; ++c)
        v[c] = h[((size_t)(b * 48 + c) * 256 + y) * 256 + tid];
    float acc = b2[0];
    for (int h4 = 0; h4 < 16; ++h4) {
        float s0 = s_b1[4*h4], s1 = s_b1[4*h4+1], s2 = s_b1[4*h4+2], s3 = s_b1[4*h4+3];
        #pragma unroll
        for (int i = 0; i < 48; ++i) {
            float4 w4 = s_w1[i * 16 + h4];
            float vi = v[i];
            s0 += vi * w4.x; s1 += vi * w4.y; s2 += vi * w4.z; s3 += vi * w4.w;
        }
        acc += gelu_f(s0) * s_w2[4*h4] + gelu_f(s1) * s_w2[4*h4+1]
             + gelu_f(s2) * s_w2[4*h4+2] + gelu_f(s3) * s_w2[4*h4+3];
    }
    out[(size_t)(b * 255 + y) * 255 + tid] = acc;
}

extern "C" void kernel_launch(void* const* d_in, const int* in_sizes, int n_in,
                              void* d_out, int out_size, void* d_ws, size_t ws_size,
                              hipStream_t stream)
{
    const float* x    = (const float*)d_in[0];
    const float* fc0w = (const float*)d_in[1];
    const float* fc0b = (const float*)d_in[2];
    const float* wc[4] = { (const float*)d_in[3], (const float*)d_in[4],
                           (const float*)d_in[5], (const float*)d_in[6] };
    const float* cw   = (const float*)d_in[7];
    const float* cb   = (const float*)d_in[8];
    const float* fc1w = (const float*)d_in[9];
    const float* fc1b = (const float*)d_in[10];
    const float* fc2w = (const float*)d_in[11];
    const float* fc2b = (const float*)d_in[12];
    float* out = (float*)d_out;
    (void)in_sizes; (void)n_in;

    // ---- batch-chunked workspace plan (same footprint as before) -----------------
    const size_t A_F     = 25165824;  // (8,48,256,256)
    const size_t PER_SHT = 139119;    // 68096 (W1 / mid alias) + 53067 (Y0) + 17956 (L1)
    int cb_n = 0;
    for (int c = 8; c >= 1; c >>= 1) {
        if ((A_F + (size_t)c * 48 * PER_SHT) * 4ull <= ws_size) { cb_n = c; break; }
    }
    if (cb_n == 0) {
        fill_kernel<<<dim3(2033), 256, 0, stream>>>(out, (long)out_size,
                                                    (float)(ws_size >> 20));
        return;
    }
    const int S = cb_n * 48;
    float* ws = (float*)d_ws;
    float* A    = ws;
    float* CH   = A + A_F;
    // L1-phase views of CH region:
    float* W1a  = CH;                           // (S,256,133)
    float* W1b  = CH + (size_t)S * 34048;
    float* Y0   = CH + (size_t)S * 68096;       // 3 x (S,133,133)
    float* L1c  = Y0 + (size_t)S * 53067;       // (S,134,134) / (S,133,133) tight
    // mid-phase views (alias the W1 region; dead before idwt_y1 writes W1):
    float* L2   = CH;                           // (S,72,72)
    float* Y1   = L2  + (size_t)S * 5184;       // 3 x (S,72,72)
    float* L3   = Y1  + (size_t)S * 3 * 5184;   // (S,41,41)
    float* Y2   = L3  + (size_t)S * 1681;       // 3 x (S,41,41)
    float* Y2m  = Y2  + (size_t)S * 3 * 1681;
    float* L3m  = Y2m + (size_t)S * 3 * 1681;

    const size_t D1 = (size_t)S * 17689, D2 = (size_t)S * 5184, D3 = (size_t)S * 1681;
    auto g = [](long n) { return dim3((unsigned)((n + 255) / 256)); };

    fc0_kernel<<<g(25165824L), 256, 0, stream>>>(x, fc0w, fc0b, A);

    for (int layer = 0; layer < 4; ++layer) {
        const float* w = wc[layer];
        for (int b0 = 0; b0 < 8; b0 += cb_n) {
            float* Ac = A + (size_t)b0 * 48 * 65536;
            // ---- fused DWT level 1: 256 -> 133 (25 tiles/sheet)
            dwt2_kernel<<<dim3(S * 25), 256, 0, stream>>>(
                    Ac, L1c, Y0, Y0 + D1, Y0 + 2 * D1, S, 256, 133, 5);
            // ---- fused DWT level 2: 133 -> 72 (9 tiles/sheet)
            dwt2_kernel<<<dim3(S * 9), 256, 0, stream>>>(
                    L1c, L2, Y1, Y1 + D2, Y1 + 2 * D2, S, 133, 72, 3);
            // ---- fused DWT level 3: 72 -> 41 (4 tiles/sheet)
            dwt2_kernel<<<dim3(S * 4), 256, 0, stream>>>(
                    L2, L3, Y2, Y2 + D3, Y2 + 2 * D3, S, 72, 41, 2);
            // ---- coarsest-level channel mixes, one launch
            mix4_kernel<<<g(4L * 48 * 1681), 256, 0, stream>>>(
                    L3, Y2, w, L3m, Y2m, (long)D3, cb_n);
            // ---- fused IDWT level 3: 41 -> 72 (overwrites L2)
            idwt2_kernel<<<dim3(S * 4), 256, 0, stream>>>(
                    L3m, Y2m, Y2m + D3, Y2m + 2 * D3, L2, S, 41, 72, 36, 2);
            // ---- fused IDWT level 2: 72 -> 134 (writes L1c as 134x134)
            idwt2_kernel<<<dim3(S * 16), 256, 0, stream>>>(
                    L2, Y1, Y1 + D2, Y1 + 2 * D2, L1c, S, 72, 134, 34, 4);
            // ---- IDWT level 1 y-synthesis: ll (S,134,134) cropped via strides
            idwt_y_pair_kernel<<<g(2L * S * 256 * 133), 256, 0, stream>>>(
                    L1c, Y0, W1a, 134, 17956, 133, 17689,
                    Y0 + D1, Y0 + 2 * D1, W1b, 133, 17689, 133, 17689, S, 133, 133);
            // ---- fused IDWT-L1 row synthesis + combine + activation, in place on Ac
            idwt_x_combine_kernel<<<dim3(cb_n * 1024), 256, 0, stream>>>(
                    W1a, W1b, Ac, cw + layer * 2304, cb + layer * 48,
                    layer < 3 ? 1 : 0);
        }
    }

    head_kernel<<<dim3(8 * 255), 256, 0, stream>>>(A, fc1w, fc1b, fc2w, fc2b, out);
}

// Round 5
// 3481.236 us; speedup vs baseline: 1.8741x; 1.8741x over previous
//
#include <hip/hip_runtime.h>
#include <math.h>

// DEC_LO exactly as in the reference; DEC_HI[k] = (-1)^(k+1) * DEC_LO[11-k]
__constant__ float F_LO[12] = {
    -0.00107730108499558f,  0.004777257511010651f, 0.0005538422009938016f,
    -0.031582039318031156f, 0.02752286553001629f,  0.09750160558707936f,
    -0.12976686756709563f,  -0.22626469396516913f, 0.3152503517092432f,
    0.7511339080215775f,    0.4946238903983854f,   0.11154074335008017f };
__constant__ float F_HI[12] = {
    -0.11154074335008017f,  0.4946238903983854f,   -0.7511339080215775f,
    0.3152503517092432f,    0.22626469396516913f,  -0.12976686756709563f,
    -0.09750160558707936f,  0.02752286553001629f,  0.031582039318031156f,
    0.0005538422009938016f, -0.004777257511010651f, -0.00107730108499558f };

__device__ __forceinline__ int reflect_idx(int i, int N) {
    while (i < 0 || i >= N) {
        if (i < 0) i = -1 - i;
        else       i = 2 * N - 1 - i;
    }
    return i;
}

__device__ __forceinline__ float gelu_f(float x) {
    return 0.5f * x * (1.0f + erff(x * 0.7071067811865475f));
}

#define GSL(total) for (long idx = (long)blockIdx.x * blockDim.x + threadIdx.x; \
                        idx < (total); idx += (long)gridDim.x * blockDim.x)

// ---------------- diagnostic fill (guard path) ------------------------------------
__global__ void fill_kernel(float* __restrict__ out, long n, float v)
{
    GSL(n) out[idx] = v;
}

// ---------------- fc0: x(8,255,255,4)@(4,48)+b -> A(8,48,256,256), zero pad to 256 --
__global__ void fc0_kernel(const float* __restrict__ x, const float* __restrict__ w,
                           const float* __restrict__ b, float* __restrict__ out)
{
    GSL(8L * 48 * 65536) {
        int xx = idx & 255;
        int y  = ((int)(idx >> 8)) & 255;
        int bc = (int)(idx >> 16);          // b*48 + c
        int c  = bc % 48;
        float v = 0.f;
        if (y < 255 && xx < 255) {
            int bb = bc / 48;
            const float* xp = x + (((size_t)(bb * 255 + y) * 255 + xx) << 2);
            v = b[c] + xp[0] * w[c] + xp[1] * w[48 + c] + xp[2] * w[96 + c] + xp[3] * w[144 + c];
        }
        out[idx] = v;
    }
}

// ---------------- fused separable 2D analysis: in (R,N,N) -> 4 subbands (R,O,O) ----
// O = (N+11)/2. Block = one 32x32 output tile of one sheet.
// Phase 1: stage a 75x75 input tile (symmetric reflection) into LDS, PARITY-SPLIT
//   per row: even cols at [m*80 + 0..37], odd cols at [m*80 + 40 + 0..36]. The
//   x-pass then reads stride-1 (conflict-free) instead of stride-2 (4-way).
// Phase 2: x-pass into REGISTERS (10 items/thread, unrolled -> no scratch).
// Phase 3: write lo/hi back into the SAME LDS buffer (75x64 <= 75x80), y-pass.
// LDS = 24000 B (was 41984) -> 6 blocks/CU instead of 3.
__global__ __launch_bounds__(256) void dwt2_kernel(
        const float* __restrict__ in, float* __restrict__ ll,
        float* __restrict__ d0, float* __restrict__ d1, float* __restrict__ d2,
        int R, int N, int O, int T)
{
    __shared__ float s_a[75 * 80];
    int tid = threadIdx.x;
    int bid = blockIdx.x;
    int tiles = T * T;
    int r = bid / tiles;
    int trem = bid % tiles;
    int V0 = (trem / T) * 32;
    int U0 = (trem % T) * 32;
    const float* sheet = in + (size_t)r * N * N;
    int gr0 = 2 * V0 - 10, gc0 = 2 * U0 - 10;
    for (int lin = tid; lin < 75 * 75; lin += 256) {
        int i = lin / 75, j = lin % 75;
        int gi = reflect_idx(gr0 + i, N);
        int gj = reflect_idx(gc0 + j, N);
        s_a[i * 80 + ((j & 1) ? 40 : 0) + (j >> 1)] = sheet[(size_t)gi * N + gj];
    }
    __syncthreads();
    // x-pass: 75 rows x 32 u = 2400 items into registers
    float rl[10], rh[10];
    #pragma unroll
    for (int it = 0; it < 10; ++it) {
        int lin = it * 256 + tid;
        if (lin < 2400) {
            int m = lin >> 5, u = lin & 31;
            const float* pe = s_a + m * 80 + u;        // even-col taps e[u..u+5]
            const float* po = pe + 40;                 // odd-col taps  o[u..u+5]
            float la = 0.f, ha = 0.f;
            #pragma unroll
            for (int t = 0; t < 6; ++t) {
                float ve = pe[t], vo = po[t];
                la += ve * F_LO[11 - 2 * t] + vo * F_LO[10 - 2 * t];
                ha += ve * F_HI[11 - 2 * t] + vo * F_HI[10 - 2 * t];
            }
            rl[it] = la; rh[it] = ha;
        }
    }
    __syncthreads();
    #pragma unroll
    for (int it = 0; it < 10; ++it) {
        int lin = it * 256 + tid;
        if (lin < 2400) {
            int m = lin >> 5, u = lin & 31;
            s_a[m * 64 + u]      = rl[it];
            s_a[m * 64 + 32 + u] = rh[it];
        }
    }
    __syncthreads();
    // y-pass: 32x32 outputs x 4 subbands
    int u = tid & 31;
    #pragma unroll
    for (int it = 0; it < 4; ++it) {
        int v = it * 8 + (tid >> 5);
        int ov = V0 + v, ou = U0 + u;
        if (ov < O && ou < O) {
            const float* pl = s_a + (2 * v) * 64 + u;
            const float* ph = pl + 32;
            float a_ll = 0.f, a_lh = 0.f, a_hl = 0.f, a_hh = 0.f;
            #pragma unroll
            for (int k = 0; k < 12; ++k) {
                float cl = F_LO[11 - k], cf = F_HI[11 - k];
                float vl = pl[k * 64], vh = ph[k * 64];
                a_ll += vl * cl;  a_lh += vl * cf;
                a_hl += vh * cl;  a_hh += vh * cf;
            }
            size_t o = ((size_t)r * O + ov) * O + ou;
            ll[o] = a_ll; d0[o] = a_lh; d1[o] = a_hl; d2[o] = a_hh;
        }
    }
}

// ---------------- fused separable 2D synthesis (interior-only levels) --------------
// ll,d0,d1,d2: (R,n,n) tight. out: (R,OD,OD), OD = 2n-10. TO = tile dim (even, <=36).
__global__ __launch_bounds__(256) void idwt2_kernel(
        const float* __restrict__ ll, const float* __restrict__ d0,
        const float* __restrict__ d1, const float* __restrict__ d2,
        float* __restrict__ out, int R, int n, int OD, int TO, int T)
{
    __shared__ float s_sub[4][24 * 24];
    __shared__ float s_wl[36 * 24];
    __shared__ float s_wh[36 * 24];
    int tid = threadIdx.x;
    int bid = blockIdx.x;
    int tiles = T * T;
    int r = bid / tiles;
    int trem = bid % tiles;
    int Y0t = (trem / T) * TO;
    int X0t = (trem % T) * TO;
    int ir0 = Y0t >> 1, ic0 = X0t >> 1;
    size_t sho = (size_t)r * n * n;
    const float* subs0 = ll + sho;
    const float* subs1 = d0 + sho;
    const float* subs2 = d1 + sho;
    const float* subs3 = d2 + sho;
    for (int lin = tid; lin < 4 * 576; lin += 256) {
        int q = lin / 576;
        int rem = lin % 576;
        int i = rem / 24, j = rem % 24;
        int gi = ir0 + i; if (gi > n - 1) gi = n - 1;   // clamped loads are unused
        int gj = ic0 + j; if (gj > n - 1) gj = n - 1;
        const float* s = (q == 0) ? subs0 : (q == 1) ? subs1 : (q == 2) ? subs2 : subs3;
        s_sub[q][rem] = s[(size_t)gi * n + gj];
    }
    __syncthreads();
    int NW = (TO >> 1) + 6;
    for (int lin = tid; lin < TO * NW; lin += 256) {
        int i = lin % NW, y = lin / NW;
        int par = y & 1;
        int roff = (y >> 1) * 24 + i;
        const float* pll = s_sub[0] + roff;
        const float* pd0 = s_sub[1] + roff;
        const float* pd1 = s_sub[2] + roff;
        const float* pd2 = s_sub[3] + roff;
        float wl = 0.f, wh = 0.f;
        #pragma unroll
        for (int t = 0; t < 6; ++t) {
            float cl = F_LO[2 * t + 1 - par], chf = F_HI[2 * t + 1 - par];
            wl += pll[t * 24] * cl + pd0[t * 24] * chf;
            wh += pd1[t * 24] * cl + pd2[t * 24] * chf;
        }
        s_wl[y * 24 + i] = wl;
        s_wh[y * 24 + i] = wh;
    }
    __syncthreads();
    for (int lin = tid; lin < TO * TO; lin += 256) {
        int tx = lin % TO, ty = lin / TO;
        int oy = Y0t + ty, ox = X0t + tx;
        if (oy >= OD || ox >= OD) continue;
        int par = tx & 1;
        const float* pl = s_wl + ty * 24 + (tx >> 1);
        const float* ph = s_wh + ty * 24 + (tx >> 1);
        float acc = 0.f;
        #pragma unroll
        for (int s = 0; s < 6; ++s)
            acc += pl[s] * F_LO[2 * s + 1 - par] + ph[s] * F_HI[2 * s + 1 - par];
        out[((size_t)r * OD + oy) * OD + ox] = acc;
    }
}

// ---------------- synthesis along y, TWO independent problems in one launch --------
__global__ void idwt_y_pair_kernel(
        const float* __restrict__ loA, const float* __restrict__ hiA, float* __restrict__ outA,
        int rslA, int sslA, int rshA, int sshA,
        const float* __restrict__ loB, const float* __restrict__ hiB, float* __restrict__ outB,
        int rslB, int sslB, int rshB, int sshB,
        int R, int n, int NX)
{
    int OY = 2 * n - 10;
    long base = (long)R * OY * NX;
    GSL(2 * base) {
        const float *lo, *hi; float* out; int rsl, ssl, rsh, ssh; long id2;
        if (idx < base) { lo=loA; hi=hiA; out=outA; rsl=rslA; ssl=sslA; rsh=rshA; ssh=sshA; id2=idx; }
        else            { lo=loB; hi=hiB; out=outB; rsl=rslB; ssl=sslB; rsh=rshB; ssh=sshB; id2=idx-base; }
        int x = (int)(id2 % NX);
        long t = id2 / NX;
        int u = (int)(t % OY);
        int r = (int)(t / OY);
        int par = u & 1;
        int i0  = u >> 1;
        float cl[6], ch[6];
        #pragma unroll
        for (int tt = 0; tt < 6; ++tt) {
            cl[tt] = F_LO[2 * tt + 1 - par];
            ch[tt] = F_HI[2 * tt + 1 - par];
        }
        const float* lop = lo + (size_t)r * ssl + (size_t)i0 * rsl + x;
        const float* hp  = hi + (size_t)r * ssh + (size_t)i0 * rsh + x;
        float acc = 0.f;
        #pragma unroll
        for (int tt = 0; tt < 6; ++tt)
            acc += lop[(size_t)tt * rsl] * cl[tt] + hp[(size_t)tt * rsh] * ch[tt];
        out[((size_t)r * OY + u) * NX + x] = acc;
    }
}

// ---------------- all four coarsest mixes in ONE launch ----------------------------
__global__ void mix4_kernel(const float* __restrict__ L3, const float* __restrict__ Y2,
                            const float* __restrict__ wc_l, float* __restrict__ L3m,
                            float* __restrict__ Y2m, long D3, int NB)
{
    const long PER = 48L * 1681;
    const size_t WKS = 48 * 48 * (size_t)1681;
    GSL(4 * PER) {
        int q = (int)(idx / PER);
        long r = idx % PER;
        const float* in = (q == 0) ? L3 : Y2 + (size_t)(q - 1) * D3;
        const float* wk = wc_l + (size_t)q * WKS;
        float* out      = (q == 0) ? L3m : Y2m + (size_t)(q - 1) * D3;
        int p = (int)(r % 1681);
        int o = (int)(r / 1681);
        float acc[8] = {0.f,0.f,0.f,0.f,0.f,0.f,0.f,0.f};
        for (int i = 0; i < 48; ++i) {
            float w = wk[(size_t)(i * 48 + o) * 1681 + p];
            for (int b = 0; b < NB; ++b)
                acc[b] += in[(size_t)(b * 48 + i) * 1681 + p] * w;
        }
        for (int b = 0; b < NB; ++b)
            out[(size_t)(b * 48 + o) * 1681 + p] = acc[b];
    }
}

// ---------------- fused: IDWT-L1 row synthesis + h = act(h1 + cw@h + cb), in place -
// Grid = NB*256*4 blocks. Block = (local batch b, row y, x-tile of 64 px). The block
// stages all 48 channels of its 64 pixels into LDS (coalesced), then 256 threads
// compute 48ch x 64px items (12 per thread). Pixel ownership is exclusive per block,
// so the in-place update of h stays race-free. The h1 tap loop is the branch-free
// parity form (parity fixed per thread -> coefficients hoisted out of the item loop).
// Verified fast shape: 36 VGPR, ~58% occupancy (rounds 2-3).
__global__ __launch_bounds__(256) void idwt_x_combine_kernel(
        const float* __restrict__ w1a, const float* __restrict__ w1b,
        float* __restrict__ h, const float* __restrict__ cw,
        const float* __restrict__ cb, int do_gelu)
{
    __shared__ float s_h[48 * 64];
    __shared__ float s_w[2304];
    __shared__ float s_b[48];
    int tid = threadIdx.x;
    int bi = blockIdx.x;
    int xt = bi & 3;
    int y  = (bi >> 2) & 255;
    int b  = bi >> 10;
    int x0 = xt << 6;
    for (int j = tid; j < 2304; j += 256) s_w[j] = cw[j];
    if (tid < 48) s_b[tid] = cb[tid];
    for (int j = tid; j < 48 * 64; j += 256) {
        int i = j >> 6, xx = j & 63;
        s_h[j] = h[((size_t)(b * 48 + i) * 256 + y) * 256 + x0 + xx];
    }
    __syncthreads();
    int xpx  = x0 + (tid & 63);
    int par  = xpx & 1;
    int i0   = xpx >> 1;               // i0+5 <= 132 < 133, no bounds check needed
    float cl[6], ch[6];
    #pragma unroll
    for (int tt = 0; tt < 6; ++tt) {
        cl[tt] = F_LO[2 * tt + 1 - par];
        ch[tt] = F_HI[2 * tt + 1 - par];
    }
    #pragma unroll
    for (int k = 0; k < 12; ++k) {
        int m = (k << 8) + tid;          // per wave: same c, xx = lane (conflict-free)
        int c  = m >> 6;
        int xx = m & 63;
        int x  = x0 + xx;
        const float* lop = w1a + ((size_t)(b * 48 + c) * 256 + y) * 133 + i0;
        const float* hp  = w1b + ((size_t)(b * 48 + c) * 256 + y) * 133 + i0;
        float h1 = 0.f;
        #pragma unroll
        for (int tt = 0; tt < 6; ++tt)
            h1 += lop[tt] * cl[tt] + hp[tt] * ch[tt];
        float h2 = s_b[c];
        const float* wr = s_w + c * 48;
        const float* vr = s_h + xx;
        #pragma unroll
        for (int i = 0; i < 48; ++i) h2 += wr[i] * vr[i << 6];
        float r = h1 + h2;
        h[((size_t)(b * 48 + c) * 256 + y) * 256 + x] = do_gelu ? gelu_f(r) : r;
    }
}

// ---------------- head: crop 255x255, gelu(h@fc1+b1)@fc2+b2 ------------------------
__global__ __launch_bounds__(256) void head_kernel(const float* __restrict__ h,
        const float* __restrict__ w1, const float* __restrict__ b1,
        const float* __restrict__ w2, const float* __restrict__ b2,
        float* __restrict__ out)
{
    __shared__ float4 s_w1[768];      // [i][hh/4]
    __shared__ float s_b1[64];
    __shared__ float s_w2[64];
    int tid = threadIdx.x;
    for (int j = tid; j < 768; j += 256) s_w1[j] = ((const float4*)w1)[j];
    if (tid < 64) { s_b1[tid] = b1[tid]; s_w2[tid] = w2[tid]; }
    __syncthreads();
    int b = blockIdx.x / 255;
    int y = blockIdx.x % 255;
    if (tid >= 255) return;
    float v[48];
    #pragma unroll
    for (int c = 0; c < 48; ++c)
        v[c] = h[((size_t)(b * 48 + c) * 256 + y) * 256 + tid];
    float acc = b2[0];
    for (int h4 = 0; h4 < 16; ++h4) {
        float s0 = s_b1[4*h4], s1 = s_b1[4*h4+1], s2 = s_b1[4*h4+2], s3 = s_b1[4*h4+3];
        #pragma unroll
        for (int i = 0; i < 48; ++i) {
            float4 w4 = s_w1[i * 16 + h4];
            float vi = v[i];
            s0 += vi * w4.x; s1 += vi * w4.y; s2 += vi * w4.z; s3 += vi * w4.w;
        }
        acc += gelu_f(s0) * s_w2[4*h4] + gelu_f(s1) * s_w2[4*h4+1]
             + gelu_f(s2) * s_w2[4*h4+2] + gelu_f(s3) * s_w2[4*h4+3];
    }
    out[(size_t)(b * 255 + y) * 255 + tid] = acc;
}

extern "C" void kernel_launch(void* const* d_in, const int* in_sizes, int n_in,
                              void* d_out, int out_size, void* d_ws, size_t ws_size,
                              hipStream_t stream)
{
    const float* x    = (const float*)d_in[0];
    const float* fc0w = (const float*)d_in[1];
    const float* fc0b = (const float*)d_in[2];
    const float* wc[4] = { (const float*)d_in[3], (const float*)d_in[4],
                           (const float*)d_in[5], (const float*)d_in[6] };
    const float* cw   = (const float*)d_in[7];
    const float* cb   = (const float*)d_in[8];
    const float* fc1w = (const float*)d_in[9];
    const float* fc1b = (const float*)d_in[10];
    const float* fc2w = (const float*)d_in[11];
    const float* fc2b = (const float*)d_in[12];
    float* out = (float*)d_out;
    (void)in_sizes; (void)n_in;

    // ---- batch-chunked workspace plan (same footprint as before) -----------------
    const size_t A_F     = 25165824;  // (8,48,256,256)
    const size_t PER_SHT = 139119;    // 68096 (W1 / mid alias) + 53067 (Y0) + 17956 (L1)
    int cb_n = 0;
    for (int c = 8; c >= 1; c >>= 1) {
        if ((A_F + (size_t)c * 48 * PER_SHT) * 4ull <= ws_size) { cb_n = c; break; }
    }
    if (cb_n == 0) {
        fill_kernel<<<dim3(2033), 256, 0, stream>>>(out, (long)out_size,
                                                    (float)(ws_size >> 20));
        return;
    }
    const int S = cb_n * 48;
    float* ws = (float*)d_ws;
    float* A    = ws;
    float* CH   = A + A_F;
    // L1-phase views of CH region:
    float* W1a  = CH;                           // (S,256,133)
    float* W1b  = CH + (size_t)S * 34048;
    float* Y0   = CH + (size_t)S * 68096;       // 3 x (S,133,133)
    float* L1c  = Y0 + (size_t)S * 53067;       // (S,134,134) / (S,133,133) tight
    // mid-phase views (alias the W1 region; dead before idwt_y1 writes W1):
    float* L2   = CH;                           // (S,72,72)
    float* Y1   = L2  + (size_t)S * 5184;       // 3 x (S,72,72)
    float* L3   = Y1  + (size_t)S * 3 * 5184;   // (S,41,41)
    float* Y2   = L3  + (size_t)S * 1681;       // 3 x (S,41,41)
    float* Y2m  = Y2  + (size_t)S * 3 * 1681;
    float* L3m  = Y2m + (size_t)S * 3 * 1681;

    const size_t D1 = (size_t)S * 17689, D2 = (size_t)S * 5184, D3 = (size_t)S * 1681;
    auto g = [](long n) { return dim3((unsigned)((n + 255) / 256)); };

    fc0_kernel<<<g(25165824L), 256, 0, stream>>>(x, fc0w, fc0b, A);

    for (int layer = 0; layer < 4; ++layer) {
        const float* w = wc[layer];
        for (int b0 = 0; b0 < 8; b0 += cb_n) {
            float* Ac = A + (size_t)b0 * 48 * 65536;
            // ---- fused DWT level 1: 256 -> 133 (25 tiles/sheet)
            dwt2_kernel<<<dim3(S * 25), 256, 0, stream>>>(
                    Ac, L1c, Y0, Y0 + D1, Y0 + 2 * D1, S, 256, 133, 5);
            // ---- fused DWT level 2: 133 -> 72 (9 tiles/sheet)
            dwt2_kernel<<<dim3(S * 9), 256, 0, stream>>>(
                    L1c, L2, Y1, Y1 + D2, Y1 + 2 * D2, S, 133, 72, 3);
            // ---- fused DWT level 3: 72 -> 41 (4 tiles/sheet)
            dwt2_kernel<<<dim3(S * 4), 256, 0, stream>>>(
                    L2, L3, Y2, Y2 + D3, Y2 + 2 * D3, S, 72, 41, 2);
            // ---- coarsest-level channel mixes, one launch
            mix4_kernel<<<g(4L * 48 * 1681), 256, 0, stream>>>(
                    L3, Y2, w, L3m, Y2m, (long)D3, cb_n);
            // ---- fused IDWT level 3: 41 -> 72 (overwrites L2)
            idwt2_kernel<<<dim3(S * 4), 256, 0, stream>>>(
                    L3m, Y2m, Y2m + D3, Y2m + 2 * D3, L2, S, 41, 72, 36, 2);
            // ---- fused IDWT level 2: 72 -> 134 (writes L1c as 134x134)
            idwt2_kernel<<<dim3(S * 16), 256, 0, stream>>>(
                    L2, Y1, Y1 + D2, Y1 + 2 * D2, L1c, S, 72, 134, 34, 4);
            // ---- IDWT level 1 y-synthesis: ll (S,134,134) cropped via strides
            idwt_y_pair_kernel<<<g(2L * S * 256 * 133), 256, 0, stream>>>(
                    L1c, Y0, W1a, 134, 17956, 133, 17689,
                    Y0 + D1, Y0 + 2 * D1, W1b, 133, 17689, 133, 17689, S, 133, 133);
            // ---- fused IDWT-L1 row synthesis + combine + activation, in place on Ac
            idwt_x_combine_kernel<<<dim3(cb_n * 1024), 256, 0, stream>>>(
                    W1a, W1b, Ac, cw + layer * 2304, cb + layer * 48,
                    layer < 3 ? 1 : 0);
        }
    }

    head_kernel<<<dim3(8 * 255), 256, 0, stream>>>(A, fc1w, fc1b, fc2w, fc2b, out);
}

// Round 6
// 2387.344 us; speedup vs baseline: 2.7328x; 1.4582x over previous
//
#include <hip/hip_runtime.h>
#include <math.h>

// DEC_LO exactly as in the reference; DEC_HI[k] = (-1)^(k+1) * DEC_LO[11-k]
__constant__ float F_LO[12] = {
    -0.00107730108499558f,  0.004777257511010651f, 0.0005538422009938016f,
    -0.031582039318031156f, 0.02752286553001629f,  0.09750160558707936f,
    -0.12976686756709563f,  -0.22626469396516913f, 0.3152503517092432f,
    0.7511339080215775f,    0.4946238903983854f,   0.11154074335008017f };
__constant__ float F_HI[12] = {
    -0.11154074335008017f,  0.4946238903983854f,   -0.7511339080215775f,
    0.3152503517092432f,    0.22626469396516913f,  -0.12976686756709563f,
    -0.09750160558707936f,  0.02752286553001629f,  0.031582039318031156f,
    0.0005538422009938016f, -0.004777257511010651f, -0.00107730108499558f };

__device__ __forceinline__ int reflect_idx(int i, int N) {
    while (i < 0 || i >= N) {
        if (i < 0) i = -1 - i;
        else       i = 2 * N - 1 - i;
    }
    return i;
}

__device__ __forceinline__ float gelu_f(float x) {
    return 0.5f * x * (1.0f + erff(x * 0.7071067811865475f));
}

#define GSL(total) for (long idx = (long)blockIdx.x * blockDim.x + threadIdx.x; \
                        idx < (total); idx += (long)gridDim.x * blockDim.x)

// ---------------- diagnostic fill (guard path) ------------------------------------
__global__ void fill_kernel(float* __restrict__ out, long n, float v)
{
    GSL(n) out[idx] = v;
}

// ---------------- fc0: x(8,255,255,4)@(4,48)+b -> A(8,48,256,256), zero pad to 256 --
__global__ void fc0_kernel(const float* __restrict__ x, const float* __restrict__ w,
                           const float* __restrict__ b, float* __restrict__ out)
{
    GSL(8L * 48 * 65536) {
        int xx = idx & 255;
        int y  = ((int)(idx >> 8)) & 255;
        int bc = (int)(idx >> 16);          // b*48 + c
        int c  = bc % 48;
        float v = 0.f;
        if (y < 255 && xx < 255) {
            int bb = bc / 48;
            const float* xp = x + (((size_t)(bb * 255 + y) * 255 + xx) << 2);
            v = b[c] + xp[0] * w[c] + xp[1] * w[48 + c] + xp[2] * w[96 + c] + xp[3] * w[144 + c];
        }
        out[idx] = v;
    }
}

// ---------------- fused separable 2D analysis: in (R,N,N) -> 4 subbands (R,O,O) ----
// O = (N+11)/2. Block = one 32x32 output tile of one sheet. Parity-split LDS input
// (conflict-free x-pass), x-pass through registers, lo/hi reuse the same buffer.
// LDS = 24000 B -> 6 blocks/CU. Verified R5.
__global__ __launch_bounds__(256) void dwt2_kernel(
        const float* __restrict__ in, float* __restrict__ ll,
        float* __restrict__ d0, float* __restrict__ d1, float* __restrict__ d2,
        int R, int N, int O, int T)
{
    __shared__ float s_a[75 * 80];
    int tid = threadIdx.x;
    int bid = blockIdx.x;
    int tiles = T * T;
    int r = bid / tiles;
    int trem = bid % tiles;
    int V0 = (trem / T) * 32;
    int U0 = (trem % T) * 32;
    const float* sheet = in + (size_t)r * N * N;
    int gr0 = 2 * V0 - 10, gc0 = 2 * U0 - 10;
    for (int lin = tid; lin < 75 * 75; lin += 256) {
        int i = lin / 75, j = lin % 75;
        int gi = reflect_idx(gr0 + i, N);
        int gj = reflect_idx(gc0 + j, N);
        s_a[i * 80 + ((j & 1) ? 40 : 0) + (j >> 1)] = sheet[(size_t)gi * N + gj];
    }
    __syncthreads();
    // x-pass: 75 rows x 32 u = 2400 items into registers
    float rl[10], rh[10];
    #pragma unroll
    for (int it = 0; it < 10; ++it) {
        int lin = it * 256 + tid;
        if (lin < 2400) {
            int m = lin >> 5, u = lin & 31;
            const float* pe = s_a + m * 80 + u;        // even-col taps e[u..u+5]
            const float* po = pe + 40;                 // odd-col taps  o[u..u+5]
            float la = 0.f, ha = 0.f;
            #pragma unroll
            for (int t = 0; t < 6; ++t) {
                float ve = pe[t], vo = po[t];
                la += ve * F_LO[11 - 2 * t] + vo * F_LO[10 - 2 * t];
                ha += ve * F_HI[11 - 2 * t] + vo * F_HI[10 - 2 * t];
            }
            rl[it] = la; rh[it] = ha;
        }
    }
    __syncthreads();
    #pragma unroll
    for (int it = 0; it < 10; ++it) {
        int lin = it * 256 + tid;
        if (lin < 2400) {
            int m = lin >> 5, u = lin & 31;
            s_a[m * 64 + u]      = rl[it];
            s_a[m * 64 + 32 + u] = rh[it];
        }
    }
    __syncthreads();
    // y-pass: 32x32 outputs x 4 subbands
    int u = tid & 31;
    #pragma unroll
    for (int it = 0; it < 4; ++it) {
        int v = it * 8 + (tid >> 5);
        int ov = V0 + v, ou = U0 + u;
        if (ov < O && ou < O) {
            const float* pl = s_a + (2 * v) * 64 + u;
            const float* ph = pl + 32;
            float a_ll = 0.f, a_lh = 0.f, a_hl = 0.f, a_hh = 0.f;
            #pragma unroll
            for (int k = 0; k < 12; ++k) {
                float cl = F_LO[11 - k], cf = F_HI[11 - k];
                float vl = pl[k * 64], vh = ph[k * 64];
                a_ll += vl * cl;  a_lh += vl * cf;
                a_hl += vh * cl;  a_hh += vh * cf;
            }
            size_t o = ((size_t)r * O + ov) * O + ou;
            ll[o] = a_ll; d0[o] = a_lh; d1[o] = a_hl; d2[o] = a_hh;
        }
    }
}

// ---------------- fused separable 2D synthesis (interior-only levels) --------------
// ll,d0,d1,d2: (R,n,n) tight. out: (R,OD,OD), OD = 2n-10. TO = tile dim (even, <=36).
__global__ __launch_bounds__(256) void idwt2_kernel(
        const float* __restrict__ ll, const float* __restrict__ d0,
        const float* __restrict__ d1, const float* __restrict__ d2,
        float* __restrict__ out, int R, int n, int OD, int TO, int T)
{
    __shared__ float s_sub[4][24 * 24];
    __shared__ float s_wl[36 * 24];
    __shared__ float s_wh[36 * 24];
    int tid = threadIdx.x;
    int bid = blockIdx.x;
    int tiles = T * T;
    int r = bid / tiles;
    int trem = bid % tiles;
    int Y0t = (trem / T) * TO;
    int X0t = (trem % T) * TO;
    int ir0 = Y0t >> 1, ic0 = X0t >> 1;
    size_t sho = (size_t)r * n * n;
    const float* subs0 = ll + sho;
    const float* subs1 = d0 + sho;
    const float* subs2 = d1 + sho;
    const float* subs3 = d2 + sho;
    for (int lin = tid; lin < 4 * 576; lin += 256) {
        int q = lin / 576;
        int rem = lin % 576;
        int i = rem / 24, j = rem % 24;
        int gi = ir0 + i; if (gi > n - 1) gi = n - 1;   // clamped loads are unused
        int gj = ic0 + j; if (gj > n - 1) gj = n - 1;
        const float* s = (q == 0) ? subs0 : (q == 1) ? subs1 : (q == 2) ? subs2 : subs3;
        s_sub[q][rem] = s[(size_t)gi * n + gj];
    }
    __syncthreads();
    int NW = (TO >> 1) + 6;
    for (int lin = tid; lin < TO * NW; lin += 256) {
        int i = lin % NW, y = lin / NW;
        int par = y & 1;
        int roff = (y >> 1) * 24 + i;
        const float* pll = s_sub[0] + roff;
        const float* pd0 = s_sub[1] + roff;
        const float* pd1 = s_sub[2] + roff;
        const float* pd2 = s_sub[3] + roff;
        float wl = 0.f, wh = 0.f;
        #pragma unroll
        for (int t = 0; t < 6; ++t) {
            float cl = F_LO[2 * t + 1 - par], chf = F_HI[2 * t + 1 - par];
            wl += pll[t * 24] * cl + pd0[t * 24] * chf;
            wh += pd1[t * 24] * cl + pd2[t * 24] * chf;
        }
        s_wl[y * 24 + i] = wl;
        s_wh[y * 24 + i] = wh;
    }
    __syncthreads();
    for (int lin = tid; lin < TO * TO; lin += 256) {
        int tx = lin % TO, ty = lin / TO;
        int oy = Y0t + ty, ox = X0t + tx;
        if (oy >= OD || ox >= OD) continue;
        int par = tx & 1;
        const float* pl = s_wl + ty * 24 + (tx >> 1);
        const float* ph = s_wh + ty * 24 + (tx >> 1);
        float acc = 0.f;
        #pragma unroll
        for (int s = 0; s < 6; ++s)
            acc += pl[s] * F_LO[2 * s + 1 - par] + ph[s] * F_HI[2 * s + 1 - par];
        out[((size_t)r * OD + oy) * OD + ox] = acc;
    }
}

// ---------------- all four coarsest mixes in ONE launch (NB compile-time) ----------
template<int NB>
__global__ void mix4_kernel(const float* __restrict__ L3, const float* __restrict__ Y2,
                            const float* __restrict__ wc_l, float* __restrict__ L3m,
                            float* __restrict__ Y2m, long D3)
{
    const long PER = 48L * 1681;
    const size_t WKS = 48 * 48 * (size_t)1681;
    GSL(4 * PER) {
        int q = (int)(idx / PER);
        long r = idx % PER;
        const float* in = (q == 0) ? L3 : Y2 + (size_t)(q - 1) * D3;
        const float* wk = wc_l + (size_t)q * WKS;
        float* out      = (q == 0) ? L3m : Y2m + (size_t)(q - 1) * D3;
        int p = (int)(r % 1681);
        int o = (int)(r / 1681);
        float acc[NB];
        #pragma unroll
        for (int b = 0; b < NB; ++b) acc[b] = 0.f;
        for (int i = 0; i < 48; ++i) {
            float w = wk[(size_t)(i * 48 + o) * 1681 + p];
            #pragma unroll
            for (int b = 0; b < NB; ++b)
                acc[b] += in[(size_t)(b * 48 + i) * 1681 + p] * w;
        }
        #pragma unroll
        for (int b = 0; b < NB; ++b)
            out[(size_t)(b * 48 + o) * 1681 + p] = acc[b];
    }
}

// ---------------- fused: IDWT-L1 (y-synth on the fly + x-synth) + channel mix ------
// Replaces idwt_y_pair + idwt_x_combine: W1a/W1b rows are computed in LDS from
// L1c (S,134,134) and Y0 (3 x (S,133,133)) instead of being materialized in HBM.
// Block = (local batch b, row y, x-tile of 64 px). Phase 1b is a short pre-barrier
// loop (2 live accumulators, block-uniform y-parity coeffs) -> no spill risk.
// Phase 2 is the verified R2/R5 combine body reading s_wl/s_wh from LDS.
__global__ __launch_bounds__(256) void idwt_l1_combine_kernel(
        const float* __restrict__ L1c, const float* __restrict__ Y0,
        float* __restrict__ h, const float* __restrict__ cw,
        const float* __restrict__ cb, int do_gelu, long D1)
{
    __shared__ float s_h[48 * 64];
    __shared__ float s_w[2304];
    __shared__ float s_b[48];
    __shared__ float s_wl[48 * 38];
    __shared__ float s_wh[48 * 38];
    int tid = threadIdx.x;
    int bi = blockIdx.x;
    int xt = bi & 3;
    int y  = (bi >> 2) & 255;
    int b  = bi >> 10;
    int x0 = xt << 6;
    int ic0 = x0 >> 1;
    // phase 1a: stage weights / bias / old h
    for (int j = tid; j < 2304; j += 256) s_w[j] = cw[j];
    if (tid < 48) s_b[tid] = cb[tid];
    for (int j = tid; j < 48 * 64; j += 256) {
        int i = j >> 6, xx = j & 63;
        s_h[j] = h[((size_t)(b * 48 + i) * 256 + y) * 256 + x0 + xx];
    }
    // phase 1b: y-synthesis of the W1 row fragments this block needs.
    // W1a[c][i] (lo) from L1c(134-stride, crop) + Y0_0; W1b[c][i] (hi) from Y0_1+Y0_2.
    // taps used downstream: (xx>>1)+tt <= 36 -> i in [0,37). rows yy..yy+5 <= 132.
    {
        int yy = y >> 1, pary = y & 1;
        float cly[6], chy[6];
        #pragma unroll
        for (int t = 0; t < 6; ++t) {
            cly[t] = F_LO[2 * t + 1 - pary];
            chy[t] = F_HI[2 * t + 1 - pary];
        }
        for (int it = tid; it < 48 * 37; it += 256) {
            int c = it / 37, i = it - c * 37;
            const float* pL = L1c + (size_t)(b * 48 + c) * 17956 + (size_t)yy * 134 + ic0 + i;
            const float* p0 = Y0  + (size_t)(b * 48 + c) * 17689 + (size_t)yy * 133 + ic0 + i;
            const float* p1 = p0 + D1;
            const float* p2 = p1 + D1;
            float wl = 0.f, wh = 0.f;
            #pragma unroll
            for (int t = 0; t < 6; ++t) {
                wl += pL[t * 134] * cly[t] + p0[t * 133] * chy[t];
                wh += p1[t * 133] * cly[t] + p2[t * 133] * chy[t];
            }
            s_wl[c * 38 + i] = wl;
            s_wh[c * 38 + i] = wh;
        }
    }
    __syncthreads();
    // phase 2: x-synthesis + channel mix + activation (verified combine body)
    int xpx = x0 + (tid & 63);
    int par = xpx & 1;
    float cl[6], ch[6];
    #pragma unroll
    for (int tt = 0; tt < 6; ++tt) {
        cl[tt] = F_LO[2 * tt + 1 - par];
        ch[tt] = F_HI[2 * tt + 1 - par];
    }
    #pragma unroll
    for (int k = 0; k < 12; ++k) {
        int m = (k << 8) + tid;          // per wave: same c, xx = lane
        int c  = m >> 6;
        int xx = m & 63;
        int x  = x0 + xx;
        const float* lop = s_wl + c * 38 + (xx >> 1);
        const float* hp  = s_wh + c * 38 + (xx >> 1);
        float h1 = 0.f;
        #pragma unroll
        for (int tt = 0; tt < 6; ++tt)
            h1 += lop[tt] * cl[tt] + hp[tt] * ch[tt];
        float h2 = s_b[c];
        const float* wr = s_w + c * 48;
        const float* vr = s_h + xx;
        #pragma unroll
        for (int i = 0; i < 48; ++i) h2 += wr[i] * vr[i << 6];
        float r = h1 + h2;
        h[((size_t)(b * 48 + c) * 256 + y) * 256 + x] = do_gelu ? gelu_f(r) : r;
    }
}

// ---------------- head: crop 255x255, gelu(h@fc1+b1)@fc2+b2 ------------------------
__global__ __launch_bounds__(256) void head_kernel(const float* __restrict__ h,
        const float* __restrict__ w1, const float* __restrict__ b1,
        const float* __restrict__ w2, const float* __restrict__ b2,
        float* __restrict__ out)
{
    __shared__ float4 s_w1[768];      // [i][hh/4]
    __shared__ float s_b1[64];
    __shared__ float s_w2[64];
    int tid = threadIdx.x;
    for (int j = tid; j < 768; j += 256) s_w1[j] = ((const float4*)w1)[j];
    if (tid < 64) { s_b1[tid] = b1[tid]; s_w2[tid] = w2[tid]; }
    __syncthreads();
    int b = blockIdx.x / 255;
    int y = blockIdx.x % 255;
    if (tid >= 255) return;
    float v[48];
    #pragma unroll
    for (int c = 0; c < 48; ++c)
        v[c] = h[((size_t)(b * 48 + c) * 256 + y) * 256 + tid];
    float acc = b2[0];
    for (int h4 = 0; h4 < 16; ++h4) {
        float s0 = s_b1[4*h4], s1 = s_b1[4*h4+1], s2 = s_b1[4*h4+2], s3 = s_b1[4*h4+3];
        #pragma unroll
        for (int i = 0; i < 48; ++i) {
            float4 w4 = s_w1[i * 16 + h4];
            float vi = v[i];
            s0 += vi * w4.x; s1 += vi * w4.y; s2 += vi * w4.z; s3 += vi * w4.w;
        }
        acc += gelu_f(s0) * s_w2[4*h4] + gelu_f(s1) * s_w2[4*h4+1]
             + gelu_f(s2) * s_w2[4*h4+2] + gelu_f(s3) * s_w2[4*h4+3];
    }
    out[(size_t)(b * 255 + y) * 255 + tid] = acc;
}

extern "C" void kernel_launch(void* const* d_in, const int* in_sizes, int n_in,
                              void* d_out, int out_size, void* d_ws, size_t ws_size,
                              hipStream_t stream)
{
    const float* x    = (const float*)d_in[0];
    const float* fc0w = (const float*)d_in[1];
    const float* fc0b = (const float*)d_in[2];
    const float* wc[4] = { (const float*)d_in[3], (const float*)d_in[4],
                           (const float*)d_in[5], (const float*)d_in[6] };
    const float* cw   = (const float*)d_in[7];
    const float* cb   = (const float*)d_in[8];
    const float* fc1w = (const float*)d_in[9];
    const float* fc1b = (const float*)d_in[10];
    const float* fc2w = (const float*)d_in[11];
    const float* fc2b = (const float*)d_in[12];
    float* out = (float*)d_out;
    (void)in_sizes; (void)n_in;

    // ---- batch-chunked workspace plan (W1 eliminated -> smaller footprint) --------
    // per sheet: Y0 3x17689=53067 + L1c 17956 + mid (L2 5184 + Y1 15552 + L3 1681
    //            + Y2 5043 + Y2m 5043 + L3m 1681 = 34184)  => 105207 floats
    const size_t A_F     = 25165824;  // (8,48,256,256)
    const size_t PER_SHT = 105207;
    int cb_n = 0;
    for (int c = 8; c >= 1; c >>= 1) {
        if ((A_F + (size_t)c * 48 * PER_SHT) * 4ull <= ws_size) { cb_n = c; break; }
    }
    if (cb_n == 0) {
        fill_kernel<<<dim3(2033), 256, 0, stream>>>(out, (long)out_size,
                                                    (float)(ws_size >> 20));
        return;
    }
    const int S = cb_n * 48;
    float* ws = (float*)d_ws;
    float* A    = ws;
    float* Y0   = A   + A_F;                    // 3 x (S,133,133)
    float* L1c  = Y0  + (size_t)S * 53067;      // (S,134,134); dwt writes 133^2 tight
    float* L2   = L1c + (size_t)S * 17956;      // (S,72,72)
    float* Y1   = L2  + (size_t)S * 5184;       // 3 x (S,72,72)
    float* L3   = Y1  + (size_t)S * 3 * 5184;   // (S,41,41)
    float* Y2   = L3  + (size_t)S * 1681;       // 3 x (S,41,41)
    float* Y2m  = Y2  + (size_t)S * 3 * 1681;
    float* L3m  = Y2m + (size_t)S * 3 * 1681;

    const size_t D1 = (size_t)S * 17689, D2 = (size_t)S * 5184, D3 = (size_t)S * 1681;
    auto g = [](long n) { return dim3((unsigned)((n + 255) / 256)); };

    fc0_kernel<<<g(25165824L), 256, 0, stream>>>(x, fc0w, fc0b, A);

    for (int layer = 0; layer < 4; ++layer) {
        const float* w = wc[layer];
        for (int b0 = 0; b0 < 8; b0 += cb_n) {
            float* Ac = A + (size_t)b0 * 48 * 65536;
            // ---- fused DWT level 1: 256 -> 133 (25 tiles/sheet)
            dwt2_kernel<<<dim3(S * 25), 256, 0, stream>>>(
                    Ac, L1c, Y0, Y0 + D1, Y0 + 2 * D1, S, 256, 133, 5);
            // ---- fused DWT level 2: 133 -> 72 (9 tiles/sheet)
            dwt2_kernel<<<dim3(S * 9), 256, 0, stream>>>(
                    L1c, L2, Y1, Y1 + D2, Y1 + 2 * D2, S, 133, 72, 3);
            // ---- fused DWT level 3: 72 -> 41 (4 tiles/sheet)
            dwt2_kernel<<<dim3(S * 4), 256, 0, stream>>>(
                    L2, L3, Y2, Y2 + D3, Y2 + 2 * D3, S, 72, 41, 2);
            // ---- coarsest-level channel mixes, one launch
            switch (cb_n) {
                case 8: mix4_kernel<8><<<g(4L*48*1681), 256, 0, stream>>>(L3, Y2, w, L3m, Y2m, (long)D3); break;
                case 4: mix4_kernel<4><<<g(4L*48*1681), 256, 0, stream>>>(L3, Y2, w, L3m, Y2m, (long)D3); break;
                case 2: mix4_kernel<2><<<g(4L*48*1681), 256, 0, stream>>>(L3, Y2, w, L3m, Y2m, (long)D3); break;
                default: mix4_kernel<1><<<g(4L*48*1681), 256, 0, stream>>>(L3, Y2, w, L3m, Y2m, (long)D3); break;
            }
            // ---- fused IDWT level 3: 41 -> 72 (overwrites L2)
            idwt2_kernel<<<dim3(S * 4), 256, 0, stream>>>(
                    L3m, Y2m, Y2m + D3, Y2m + 2 * D3, L2, S, 41, 72, 36, 2);
            // ---- fused IDWT level 2: 72 -> 134 (writes L1c as 134x134)
            idwt2_kernel<<<dim3(S * 16), 256, 0, stream>>>(
                    L2, Y1, Y1 + D2, Y1 + 2 * D2, L1c, S, 72, 134, 34, 4);
            // ---- fused IDWT level 1 + combine + activation, in place on Ac
            idwt_l1_combine_kernel<<<dim3(cb_n * 1024), 256, 0, stream>>>(
                    L1c, Y0, Ac, cw + layer * 2304, cb + layer * 48,
                    layer < 3 ? 1 : 0, (long)D1);
        }
    }

    head_kernel<<<dim3(8 * 255), 256, 0, stream>>>(A, fc1w, fc1b, fc2w, fc2b, out);
}

// Round 8
// 2336.070 us; speedup vs baseline: 2.7928x; 1.0219x over previous
//
#include <hip/hip_runtime.h>
#include <math.h>

// DEC_LO exactly as in the reference; DEC_HI[k] = (-1)^(k+1) * DEC_LO[11-k]
__constant__ float F_LO[12] = {
    -0.00107730108499558f,  0.004777257511010651f, 0.0005538422009938016f,
    -0.031582039318031156f, 0.02752286553001629f,  0.09750160558707936f,
    -0.12976686756709563f,  -0.22626469396516913f, 0.3152503517092432f,
    0.7511339080215775f,    0.4946238903983854f,   0.11154074335008017f };
__constant__ float F_HI[12] = {
    -0.11154074335008017f,  0.4946238903983854f,   -0.7511339080215775f,
    0.3152503517092432f,    0.22626469396516913f,  -0.12976686756709563f,
    -0.09750160558707936f,  0.02752286553001629f,  0.031582039318031156f,
    0.0005538422009938016f, -0.004777257511010651f, -0.00107730108499558f };

__device__ __forceinline__ int reflect_idx(int i, int N) {
    while (i < 0 || i >= N) {
        if (i < 0) i = -1 - i;
        else       i = 2 * N - 1 - i;
    }
    return i;
}

__device__ __forceinline__ float gelu_f(float x) {
    return 0.5f * x * (1.0f + erff(x * 0.7071067811865475f));
}

#define GSL(total) for (long idx = (long)blockIdx.x * blockDim.x + threadIdx.x; \
                        idx < (total); idx += (long)gridDim.x * blockDim.x)

// ---------------- diagnostic fill (guard path) ------------------------------------
__global__ void fill_kernel(float* __restrict__ out, long n, float v)
{
    GSL(n) out[idx] = v;
}

// ---------------- fc0: x(8,255,255,4)@(4,48)+b -> A(8,48,256,256), zero pad to 256 --
__global__ void fc0_kernel(const float* __restrict__ x, const float* __restrict__ w,
                           const float* __restrict__ b, float* __restrict__ out)
{
    GSL(8L * 48 * 65536) {
        int xx = idx & 255;
        int y  = ((int)(idx >> 8)) & 255;
        int bc = (int)(idx >> 16);          // b*48 + c
        int c  = bc % 48;
        float v = 0.f;
        if (y < 255 && xx < 255) {
            int bb = bc / 48;
            const float* xp = x + (((size_t)(bb * 255 + y) * 255 + xx) << 2);
            v = b[c] + xp[0] * w[c] + xp[1] * w[48 + c] + xp[2] * w[96 + c] + xp[3] * w[144 + c];
        }
        out[idx] = v;
    }
}

// ---------------- fused separable 2D analysis: in (R,N,N) -> 4 subbands (R,O,O) ----
// O = (N+11)/2. Block = one 32x32 output tile of one sheet. Parity-split LDS input
// (conflict-free x-pass), x-pass through registers, lo/hi reuse the same buffer.
// LDS = 24000 B -> 6 blocks/CU. Verified R5.
__global__ __launch_bounds__(256) void dwt2_kernel(
        const float* __restrict__ in, float* __restrict__ ll,
        float* __restrict__ d0, float* __restrict__ d1, float* __restrict__ d2,
        int R, int N, int O, int T)
{
    __shared__ float s_a[75 * 80];
    int tid = threadIdx.x;
    int bid = blockIdx.x;
    int tiles = T * T;
    int r = bid / tiles;
    int trem = bid % tiles;
    int V0 = (trem / T) * 32;
    int U0 = (trem % T) * 32;
    const float* sheet = in + (size_t)r * N * N;
    int gr0 = 2 * V0 - 10, gc0 = 2 * U0 - 10;
    for (int lin = tid; lin < 75 * 75; lin += 256) {
        int i = lin / 75, j = lin % 75;
        int gi = reflect_idx(gr0 + i, N);
        int gj = reflect_idx(gc0 + j, N);
        s_a[i * 80 + ((j & 1) ? 40 : 0) + (j >> 1)] = sheet[(size_t)gi * N + gj];
    }
    __syncthreads();
    // x-pass: 75 rows x 32 u = 2400 items into registers
    float rl[10], rh[10];
    #pragma unroll
    for (int it = 0; it < 10; ++it) {
        int lin = it * 256 + tid;
        if (lin < 2400) {
            int m = lin >> 5, u = lin & 31;
            const float* pe = s_a + m * 80 + u;        // even-col taps e[u..u+5]
            const float* po = pe + 40;                 // odd-col taps  o[u..u+5]
            float la = 0.f, ha = 0.f;
            #pragma unroll
            for (int t = 0; t < 6; ++t) {
                float ve = pe[t], vo = po[t];
                la += ve * F_LO[11 - 2 * t] + vo * F_LO[10 - 2 * t];
                ha += ve * F_HI[11 - 2 * t] + vo * F_HI[10 - 2 * t];
            }
            rl[it] = la; rh[it] = ha;
        }
    }
    __syncthreads();
    #pragma unroll
    for (int it = 0; it < 10; ++it) {
        int lin = it * 256 + tid;
        if (lin < 2400) {
            int m = lin >> 5, u = lin & 31;
            s_a[m * 64 + u]      = rl[it];
            s_a[m * 64 + 32 + u] = rh[it];
        }
    }
    __syncthreads();
    // y-pass: 32x32 outputs x 4 subbands
    int u = tid & 31;
    #pragma unroll
    for (int it = 0; it < 4; ++it) {
        int v = it * 8 + (tid >> 5);
        int ov = V0 + v, ou = U0 + u;
        if (ov < O && ou < O) {
            const float* pl = s_a + (2 * v) * 64 + u;
            const float* ph = pl + 32;
            float a_ll = 0.f, a_lh = 0.f, a_hl = 0.f, a_hh = 0.f;
            #pragma unroll
            for (int k = 0; k < 12; ++k) {
                float cl = F_LO[11 - k], cf = F_HI[11 - k];
                float vl = pl[k * 64], vh = ph[k * 64];
                a_ll += vl * cl;  a_lh += vl * cf;
                a_hl += vh * cl;  a_hh += vh * cf;
            }
            size_t o = ((size_t)r * O + ov) * O + ou;
            ll[o] = a_ll; d0[o] = a_lh; d1[o] = a_hl; d2[o] = a_hh;
        }
    }
}

// ---------------- fused separable 2D synthesis (interior-only levels) --------------
// ll,d0,d1,d2: (R,n,n) tight. out: (R,OD,OD), OD = 2n-10. TO = tile dim (even, <=36).
__global__ __launch_bounds__(256) void idwt2_kernel(
        const float* __restrict__ ll, const float* __restrict__ d0,
        const float* __restrict__ d1, const float* __restrict__ d2,
        float* __restrict__ out, int R, int n, int OD, int TO, int T)
{
    __shared__ float s_sub[4][24 * 24];
    __shared__ float s_wl[36 * 24];
    __shared__ float s_wh[36 * 24];
    int tid = threadIdx.x;
    int bid = blockIdx.x;
    int tiles = T * T;
    int r = bid / tiles;
    int trem = bid % tiles;
    int Y0t = (trem / T) * TO;
    int X0t = (trem % T) * TO;
    int ir0 = Y0t >> 1, ic0 = X0t >> 1;
    size_t sho = (size_t)r * n * n;
    const float* subs0 = ll + sho;
    const float* subs1 = d0 + sho;
    const float* subs2 = d1 + sho;
    const float* subs3 = d2 + sho;
    for (int lin = tid; lin < 4 * 576; lin += 256) {
        int q = lin / 576;
        int rem = lin % 576;
        int i = rem / 24, j = rem % 24;
        int gi = ir0 + i; if (gi > n - 1) gi = n - 1;   // clamped loads are unused
        int gj = ic0 + j; if (gj > n - 1) gj = n - 1;
        const float* s = (q == 0) ? subs0 : (q == 1) ? subs1 : (q == 2) ? subs2 : subs3;
        s_sub[q][rem] = s[(size_t)gi * n + gj];
    }
    __syncthreads();
    int NW = (TO >> 1) + 6;
    for (int lin = tid; lin < TO * NW; lin += 256) {
        int i = lin % NW, y = lin / NW;
        int par = y & 1;
        int roff = (y >> 1) * 24 + i;
        const float* pll = s_sub[0] + roff;
        const float* pd0 = s_sub[1] + roff;
        const float* pd1 = s_sub[2] + roff;
        const float* pd2 = s_sub[3] + roff;
        float wl = 0.f, wh = 0.f;
        #pragma unroll
        for (int t = 0; t < 6; ++t) {
            float cl = F_LO[2 * t + 1 - par], chf = F_HI[2 * t + 1 - par];
            wl += pll[t * 24] * cl + pd0[t * 24] * chf;
            wh += pd1[t * 24] * cl + pd2[t * 24] * chf;
        }
        s_wl[y * 24 + i] = wl;
        s_wh[y * 24 + i] = wh;
    }
    __syncthreads();
    for (int lin = tid; lin < TO * TO; lin += 256) {
        int tx = lin % TO, ty = lin / TO;
        int oy = Y0t + ty, ox = X0t + tx;
        if (oy >= OD || ox >= OD) continue;
        int par = tx & 1;
        const float* pl = s_wl + ty * 24 + (tx >> 1);
        const float* ph = s_wh + ty * 24 + (tx >> 1);
        float acc = 0.f;
        #pragma unroll
        for (int s = 0; s < 6; ++s)
            acc += pl[s] * F_LO[2 * s + 1 - par] + ph[s] * F_HI[2 * s + 1 - par];
        out[((size_t)r * OD + oy) * OD + ox] = acc;
    }
}

// ---------------- all four coarsest mixes in ONE launch (NB compile-time) ----------
template<int NB>
__global__ void mix4_kernel(const float* __restrict__ L3, const float* __restrict__ Y2,
                            const float* __restrict__ wc_l, float* __restrict__ L3m,
                            float* __restrict__ Y2m, long D3)
{
    const long PER = 48L * 1681;
    const size_t WKS = 48 * 48 * (size_t)1681;
    GSL(4 * PER) {
        int q = (int)(idx / PER);
        long r = idx % PER;
        const float* in = (q == 0) ? L3 : Y2 + (size_t)(q - 1) * D3;
        const float* wk = wc_l + (size_t)q * WKS;
        float* out      = (q == 0) ? L3m : Y2m + (size_t)(q - 1) * D3;
        int p = (int)(r % 1681);
        int o = (int)(r / 1681);
        float acc[NB];
        #pragma unroll
        for (int b = 0; b < NB; ++b) acc[b] = 0.f;
        for (int i = 0; i < 48; ++i) {
            float w = wk[(size_t)(i * 48 + o) * 1681 + p];
            #pragma unroll
            for (int b = 0; b < NB; ++b)
                acc[b] += in[(size_t)(b * 48 + i) * 1681 + p] * w;
        }
        #pragma unroll
        for (int b = 0; b < NB; ++b)
            out[(size_t)(b * 48 + o) * 1681 + p] = acc[b];
    }
}

// ---------------- fused: IDWT-L1 (y-synth on the fly + x-synth) + channel mix ------
// Phase 2 restructured (R6->R7): per thread, xx = tid&63 is FIXED across all 12
// items (c = 4k + wid). Hoist the 48 s_h reads into registers ONCE (fully unrolled,
// static indexing -> no scratch), read weights as wave-uniform float4 broadcasts,
// keep ONE scalar accumulator per item and store immediately (R4 spill lesson).
__global__ __launch_bounds__(256) void idwt_l1_combine_kernel(
        const float* __restrict__ L1c, const float* __restrict__ Y0,
        float* __restrict__ h, const float* __restrict__ cw,
        const float* __restrict__ cb, int do_gelu, long D1)
{
    __shared__ float s_h[48 * 64];
    __shared__ float s_w[2304];
    __shared__ float s_b[48];
    __shared__ float s_wl[48 * 38];
    __shared__ float s_wh[48 * 38];
    int tid = threadIdx.x;
    int bi = blockIdx.x;
    int xt = bi & 3;
    int y  = (bi >> 2) & 255;
    int b  = bi >> 10;
    int x0 = xt << 6;
    int ic0 = x0 >> 1;
    // phase 1a: stage weights / bias / old h
    for (int j = tid; j < 2304; j += 256) s_w[j] = cw[j];
    if (tid < 48) s_b[tid] = cb[tid];
    for (int j = tid; j < 48 * 64; j += 256) {
        int i = j >> 6, xx = j & 63;
        s_h[j] = h[((size_t)(b * 48 + i) * 256 + y) * 256 + x0 + xx];
    }
    // phase 1b: y-synthesis of the W1 row fragments this block needs.
    {
        int yy = y >> 1, pary = y & 1;
        float cly[6], chy[6];
        #pragma unroll
        for (int t = 0; t < 6; ++t) {
            cly[t] = F_LO[2 * t + 1 - pary];
            chy[t] = F_HI[2 * t + 1 - pary];
        }
        for (int it = tid; it < 48 * 37; it += 256) {
            int c = it / 37, i = it - c * 37;
            const float* pL = L1c + (size_t)(b * 48 + c) * 17956 + (size_t)yy * 134 + ic0 + i;
            const float* p0 = Y0  + (size_t)(b * 48 + c) * 17689 + (size_t)yy * 133 + ic0 + i;
            const float* p1 = p0 + D1;
            const float* p2 = p1 + D1;
            float wl = 0.f, wh = 0.f;
            #pragma unroll
            for (int t = 0; t < 6; ++t) {
                wl += pL[t * 134] * cly[t] + p0[t * 133] * chy[t];
                wh += p1[t * 133] * cly[t] + p2[t * 133] * chy[t];
            }
            s_wl[c * 38 + i] = wl;
            s_wh[c * 38 + i] = wh;
        }
    }
    __syncthreads();
    // phase 2: x-synthesis + channel mix + activation
    int xx  = tid & 63;
    int wid = tid >> 6;
    int x   = x0 + xx;
    int par = x & 1;
    int i0  = xx >> 1;
    float cl[6], ch[6];
    #pragma unroll
    for (int tt = 0; tt < 6; ++tt) {
        cl[tt] = F_LO[2 * tt + 1 - par];
        ch[tt] = F_HI[2 * tt + 1 - par];
    }
    // hoist this pixel's 48 input channels into registers (read s_h once, not 12x)
    float vi[48];
    #pragma unroll
    for (int i = 0; i < 48; ++i) vi[i] = s_h[(i << 6) + xx];
    #pragma unroll
    for (int k = 0; k < 12; ++k) {
        int c = (k << 2) + wid;                 // same coverage as m=(k<<8)+tid
        const float* lop = s_wl + c * 38 + i0;
        const float* hp  = s_wh + c * 38 + i0;
        float h1 = 0.f;
        #pragma unroll
        for (int tt = 0; tt < 6; ++tt)
            h1 += lop[tt] * cl[tt] + hp[tt] * ch[tt];
        float h2 = s_b[c];
        const float4* w4 = (const float4*)(s_w + c * 48);   // wave-uniform broadcast
        #pragma unroll
        for (int i4 = 0; i4 < 12; ++i4) {
            float4 w = w4[i4];
            h2 += w.x * vi[4 * i4] + w.y * vi[4 * i4 + 1]
                + w.z * vi[4 * i4 + 2] + w.w * vi[4 * i4 + 3];
        }
        float r = h1 + h2;
        h[((size_t)(b * 48 + c) * 256 + y) * 256 + x] = do_gelu ? gelu_f(r) : r;
    }
}

// ---------------- head: crop 255x255, gelu(h@fc1+b1)@fc2+b2 ------------------------
__global__ __launch_bounds__(256) void head_kernel(const float* __restrict__ h,
        const float* __restrict__ w1, const float* __restrict__ b1,
        const float* __restrict__ w2, const float* __restrict__ b2,
        float* __restrict__ out)
{
    __shared__ float4 s_w1[768];      // [i][hh/4]
    __shared__ float s_b1[64];
    __shared__ float s_w2[64];
    int tid = threadIdx.x;
    for (int j = tid; j < 768; j += 256) s_w1[j] = ((const float4*)w1)[j];
    if (tid < 64) { s_b1[tid] = b1[tid]; s_w2[tid] = w2[tid]; }
    __syncthreads();
    int b = blockIdx.x / 255;
    int y = blockIdx.x % 255;
    if (tid >= 255) return;
    float v[48];
    #pragma unroll
    for (int c = 0; c < 48; ++c)
        v[c] = h[((size_t)(b * 48 + c) * 256 + y) * 256 + tid];
    float acc = b2[0];
    for (int h4 = 0; h4 < 16; ++h4) {
        float s0 = s_b1[4*h4], s1 = s_b1[4*h4+1], s2 = s_b1[4*h4+2], s3 = s_b1[4*h4+3];
        #pragma unroll
        for (int i = 0; i < 48; ++i) {
            float4 w4 = s_w1[i * 16 + h4];
            float vi = v[i];
            s0 += vi * w4.x; s1 += vi * w4.y; s2 += vi * w4.z; s3 += vi * w4.w;
        }
        acc += gelu_f(s0) * s_w2[4*h4] + gelu_f(s1) * s_w2[4*h4+1]
             + gelu_f(s2) * s_w2[4*h4+2] + gelu_f(s3) * s_w2[4*h4+3];
    }
    out[(size_t)(b * 255 + y) * 255 + tid] = acc;
}

extern "C" void kernel_launch(void* const* d_in, const int* in_sizes, int n_in,
                              void* d_out, int out_size, void* d_ws, size_t ws_size,
                              hipStream_t stream)
{
    const float* x    = (const float*)d_in[0];
    const float* fc0w = (const float*)d_in[1];
    const float* fc0b = (const float*)d_in[2];
    const float* wc[4] = { (const float*)d_in[3], (const float*)d_in[4],
                           (const float*)d_in[5], (const float*)d_in[6] };
    const float* cw   = (const float*)d_in[7];
    const float* cb   = (const float*)d_in[8];
    const float* fc1w = (const float*)d_in[9];
    const float* fc1b = (const float*)d_in[10];
    const float* fc2w = (const float*)d_in[11];
    const float* fc2b = (const float*)d_in[12];
    float* out = (float*)d_out;
    (void)in_sizes; (void)n_in;

    // ---- batch-chunked workspace plan --------------------------------------------
    // per sheet: Y0 3x17689=53067 + L1c 17956 + mid (L2 5184 + Y1 15552 + L3 1681
    //            + Y2 5043 + Y2m 5043 + L3m 1681 = 34184)  => 105207 floats
    const size_t A_F     = 25165824;  // (8,48,256,256)
    const size_t PER_SHT = 105207;
    int cb_n = 0;
    for (int c = 8; c >= 1; c >>= 1) {
        if ((A_F + (size_t)c * 48 * PER_SHT) * 4ull <= ws_size) { cb_n = c; break; }
    }
    if (cb_n == 0) {
        fill_kernel<<<dim3(2033), 256, 0, stream>>>(out, (long)out_size,
                                                    (float)(ws_size >> 20));
        return;
    }
    const int S = cb_n * 48;
    float* ws = (float*)d_ws;
    float* A    = ws;
    float* Y0   = A   + A_F;                    // 3 x (S,133,133)
    float* L1c  = Y0  + (size_t)S * 53067;      // (S,134,134); dwt writes 133^2 tight
    float* L2   = L1c + (size_t)S * 17956;      // (S,72,72)
    float* Y1   = L2  + (size_t)S * 5184;       // 3 x (S,72,72)
    float* L3   = Y1  + (size_t)S * 3 * 5184;   // (S,41,41)
    float* Y2   = L3  + (size_t)S * 1681;       // 3 x (S,41,41)
    float* Y2m  = Y2  + (size_t)S * 3 * 1681;
    float* L3m  = Y2m + (size_t)S * 3 * 1681;

    const size_t D1 = (size_t)S * 17689, D2 = (size_t)S * 5184, D3 = (size_t)S * 1681;
    auto g = [](long n) { return dim3((unsigned)((n + 255) / 256)); };

    fc0_kernel<<<g(25165824L), 256, 0, stream>>>(x, fc0w, fc0b, A);

    for (int layer = 0; layer < 4; ++layer) {
        const float* w = wc[layer];
        for (int b0 = 0; b0 < 8; b0 += cb_n) {
            float* Ac = A + (size_t)b0 * 48 * 65536;
            // ---- fused DWT level 1: 256 -> 133 (25 tiles/sheet)
            dwt2_kernel<<<dim3(S * 25), 256, 0, stream>>>(
                    Ac, L1c, Y0, Y0 + D1, Y0 + 2 * D1, S, 256, 133, 5);
            // ---- fused DWT level 2: 133 -> 72 (9 tiles/sheet)
            dwt2_kernel<<<dim3(S * 9), 256, 0, stream>>>(
                    L1c, L2, Y1, Y1 + D2, Y1 + 2 * D2, S, 133, 72, 3);
            // ---- fused DWT level 3: 72 -> 41 (4 tiles/sheet)
            dwt2_kernel<<<dim3(S * 4), 256, 0, stream>>>(
                    L2, L3, Y2, Y2 + D3, Y2 + 2 * D3, S, 72, 41, 2);
            // ---- coarsest-level channel mixes, one launch
            switch (cb_n) {
                case 8: mix4_kernel<8><<<g(4L*48*1681), 256, 0, stream>>>(L3, Y2, w, L3m, Y2m, (long)D3); break;
                case 4: mix4_kernel<4><<<g(4L*48*1681), 256, 0, stream>>>(L3, Y2, w, L3m, Y2m, (long)D3); break;
                case 2: mix4_kernel<2><<<g(4L*48*1681), 256, 0, stream>>>(L3, Y2, w, L3m, Y2m, (long)D3); break;
                default: mix4_kernel<1><<<g(4L*48*1681), 256, 0, stream>>>(L3, Y2, w, L3m, Y2m, (long)D3); break;
            }
            // ---- fused IDWT level 3: 41 -> 72 (overwrites L2)
            idwt2_kernel<<<dim3(S * 4), 256, 0, stream>>>(
                    L3m, Y2m, Y2m + D3, Y2m + 2 * D3, L2, S, 41, 72, 36, 2);
            // ---- fused IDWT level 2: 72 -> 134 (writes L1c as 134x134)
            idwt2_kernel<<<dim3(S * 16), 256, 0, stream>>>(
                    L2, Y1, Y1 + D2, Y1 + 2 * D2, L1c, S, 72, 134, 34, 4);
            // ---- fused IDWT level 1 + combine + activation, in place on Ac
            idwt_l1_combine_kernel<<<dim3(cb_n * 1024), 256, 0, stream>>>(
                    L1c, Y0, Ac, cw + layer * 2304, cb + layer * 48,
                    layer < 3 ? 1 : 0, (long)D1);
        }
    }

    head_kernel<<<dim3(8 * 255), 256, 0, stream>>>(A, fc1w, fc1b, fc2w, fc2b, out);
}